// Round 4
// baseline (406.835 us; speedup 1.0000x reference)
//
#include <hip/hip_runtime.h>
#include <stdint.h>

constexpr int N = 65536, K = 512, F = 512;
constexpr float ASCALE = 127.0f / 3.0f;   // activation scale (fixed bound 3.0)

typedef short frag8 __attribute__((ext_vector_type(8)));   // 8 bf16 = 4 VGPRs
typedef float floatx4 __attribute__((ext_vector_type(4))); // MFMA C/D

// round-half-even then clip to [-127,127]; result integer-valued fp32
__device__ __forceinline__ float qclamp(float v) {
    float q = rintf(v * ASCALE);
    return fminf(fmaxf(q, -127.0f), 127.0f);   // folds to v_med3_f32
}
// bf16-truncate two integer-valued fp32 into one packed u32 (exact: |v|<=127)
__device__ __forceinline__ unsigned packbf(float a, float b) {
    union { float f; unsigned u; } ua, ub; ua.f = a; ub.f = b;
    return __builtin_amdgcn_perm(ub.u, ua.u, 0x07060302u);  // [a.hi16 | b.hi16]
}

// --- phase 1: per-column abs-max (coalesced) via bit-atomicMax ---
__global__ void wmax_kernel(const float* __restrict__ kern,
                            unsigned int* __restrict__ wmax) {
    int col = threadIdx.x;
    int r0 = blockIdx.x * 64;
    float m = 0.f;
    #pragma unroll 8
    for (int r = 0; r < 64; ++r)
        m = fmaxf(m, fabsf(kern[(size_t)(r0 + r) * F + col]));
    union { float f; unsigned u; } c; c.f = m;   // positive floats order as uints
    atomicMax(wmax + col, c.u);
}

// --- phase 2: quantize + transpose -> wT[f][k] bf16; dscale[f] ---
__global__ void quantw_kernel(const float* __restrict__ kern,
                              const unsigned int* __restrict__ wmax,
                              unsigned short* __restrict__ wT,
                              float* __restrict__ dscale) {
    __shared__ float tile[64][65];
    int kb = blockIdx.x >> 3, fb = blockIdx.x & 7;
    int t = threadIdx.x;
    int c = t & 63, r4 = t >> 6;
    #pragma unroll
    for (int p = 0; p < 16; ++p) {
        int r = p * 4 + r4;
        tile[r][c] = kern[(size_t)(kb * 64 + r) * F + fb * 64 + c];
    }
    __syncthreads();
    #pragma unroll
    for (int p = 0; p < 16; ++p) {
        int fr = p * 4 + r4;
        union { float f; unsigned u; } mb; mb.u = wmax[fb * 64 + fr];
        float wsc = 127.0f / fmaxf(mb.f, 1e-7f);
        float q = rintf(tile[c][fr] * wsc);
        q = fminf(fmaxf(q, -127.0f), 127.0f);
        union { float f; unsigned u; } qu; qu.f = q;
        wT[(size_t)(fb * 64 + fr) * K + kb * 64 + c] = (unsigned short)(qu.u >> 16);
    }
    if (kb == 0 && t < 64) {
        int f = fb * 64 + t;
        union { float f; unsigned u; } mb; mb.u = wmax[f];
        dscale[f] = 3.0f * fmaxf(mb.f, 1e-7f) / 16129.0f;  // 1/(a_scale*w_scale)
    }
}

// --- phase 3: LDS-free, barrier-free fused GEMM ---
// 2048 blocks x 256 threads (4 waves). Block: 32 rows x all 512 cols (x read
// once from HBM). Wave: 32x128 tile = 2mt x 8nt of 16x16x32 bf16 MFMA.
// A: lanes load x fp32 DIRECTLY (K-contiguous frag), quantize in regs.
// B: wT (512 KB) is L2-resident; frags load directly from global.
// No LDS, no __syncthreads -> no vmcnt(0) drains; compiler pipelines freely.
__global__ __launch_bounds__(256, 3)
void gemm_kernel(const float* __restrict__ x,
                 const unsigned short* __restrict__ wT,
                 const float* __restrict__ dscale,
                 const float* __restrict__ bias,
                 float* __restrict__ out) {
    int t = threadIdx.x;
    int lane = t & 63, wave = t >> 6;
    int bm = blockIdx.x;
    int m16 = lane & 15, quad = lane >> 4;

    floatx4 acc[2][8];
    #pragma unroll
    for (int i = 0; i < 2; ++i)
        #pragma unroll
        for (int j = 0; j < 8; ++j) acc[i][j] = (floatx4){0.f, 0.f, 0.f, 0.f};

    // A: lane (m16,quad) covers x[bm*32 + mt*16 + m16][kt*32 + quad*8 .. +8]
    const float* xb = x + (size_t)(bm * 32 + m16) * K + quad * 8;
    // B: lane (m16,quad) covers wT[wave*128 + nt*16 + m16][kt*32 + quad*8 .. +8]
    const unsigned short* wb = wT + (size_t)(wave * 128 + m16) * K + quad * 8;

    #pragma unroll
    for (int kt = 0; kt < 16; ++kt) {
        frag8 af[2];
        #pragma unroll
        for (int mt = 0; mt < 2; ++mt) {
            const float* p = xb + (size_t)(mt * 16) * K + kt * 32;
            float4 u = *(const float4*)p;
            float4 v = *(const float4*)(p + 4);
            union { frag8 f; uint4 q; } fq;
            fq.q.x = packbf(qclamp(u.x), qclamp(u.y));
            fq.q.y = packbf(qclamp(u.z), qclamp(u.w));
            fq.q.z = packbf(qclamp(v.x), qclamp(v.y));
            fq.q.w = packbf(qclamp(v.z), qclamp(v.w));
            af[mt] = fq.f;
        }
        #pragma unroll
        for (int nt = 0; nt < 8; ++nt) {
            frag8 bf = *(const frag8*)(wb + (size_t)(nt * 16) * K + kt * 32);
            acc[0][nt] = __builtin_amdgcn_mfma_f32_16x16x32_bf16(
                af[0], bf, acc[0][nt], 0, 0, 0);
            acc[1][nt] = __builtin_amdgcn_mfma_f32_16x16x32_bf16(
                af[1], bf, acc[1][nt], 0, 0, 0);
        }
    }

    // epilogue: C layout col=lane&15, row=quad*4+reg (m89/m91-verified)
    #pragma unroll
    for (int nt = 0; nt < 8; ++nt) {
        int col = wave * 128 + nt * 16 + m16;
        float ds = dscale[col], bv = bias[col];
        #pragma unroll
        for (int mt = 0; mt < 2; ++mt) {
            size_t row = (size_t)bm * 32 + mt * 16 + quad * 4;
            #pragma unroll
            for (int r = 0; r < 4; ++r)
                out[(row + r) * F + col] = acc[mt][nt][r] * ds + bv;
        }
    }
}

extern "C" void kernel_launch(void* const* d_in, const int* in_sizes, int n_in,
                              void* d_out, int out_size, void* d_ws, size_t ws_size,
                              hipStream_t stream) {
    const float* x    = (const float*)d_in[0];
    const float* kern = (const float*)d_in[1];
    const float* bias = (const float*)d_in[2];
    float* out = (float*)d_out;

    unsigned short* wT = (unsigned short*)d_ws;                 // 512 KB
    float* dscale = (float*)((char*)d_ws + (size_t)K * F * 2);  // 2 KB
    unsigned int* wmax = (unsigned int*)((char*)d_ws + (size_t)K * F * 2 + 2048);

    hipMemsetAsync(wmax, 0, F * sizeof(unsigned int), stream);
    wmax_kernel<<<8, 512, 0, stream>>>(kern, wmax);
    quantw_kernel<<<64, 256, 0, stream>>>(kern, wmax, wT, dscale);
    gemm_kernel<<<N / 32, 256, 0, stream>>>(x, wT, dscale, bias, out);
}